// Round 11
// baseline (65.539 us; speedup 1.0000x reference)
//
#include <hip/hip_runtime.h>

// Problem: SpatialTransform
//   x: (16,256,256,32) f32 -> out: (16,256,256,32) f32
//   theta = mean_pool(x) @ W_loc + b_loc;  out = bilinear_sample(x, affine_grid(theta))
//
// R10 lesson: write path innocent (NT ~ plain), preamble size irrelevant.
// Plateau theory: interp bound by L2/L3 read-request volume (4 corner loads
// per px = 512MB requests). R11: vertical 8-px column per thread; row k's
// bottom corner pair == row k+1's top pair (exact index check, any theta)
// -> 2 loads + 1 store per px steady-state. No LDS, no occupancy cost.

#define NIMG 16
#define HDIM 256
#define WDIM 256
#define CH   32
#define HW   (HDIM * WDIM)
#define BPI  64    // sum-kernel blocks per image

typedef float f32x4 __attribute__((ext_vector_type(4)));

// ---------------------------------------------------------------------------
// Kernel 1: per-(n,c) partial sums. 1024 blocks, 4 independent acc chains.
// partials layout: [BPI][NIMG][CH]   (R6-proven, ~HBM read floor)
// ---------------------------------------------------------------------------
__global__ __launch_bounds__(256) void st_sum_kernel(
    const float* __restrict__ x, float* __restrict__ partials) {
    const int n   = blockIdx.x >> 6;
    const int blk = blockIdx.x & (BPI - 1);
    const int tid = threadIdx.x;
    const int cg  = tid & 7;
    const int sp  = tid >> 3;

    const float4* xp = (const float4*)(x + (size_t)n * HW * CH);
    float4 a0 = make_float4(0.f, 0.f, 0.f, 0.f);
    float4 a1 = make_float4(0.f, 0.f, 0.f, 0.f);
    float4 a2 = make_float4(0.f, 0.f, 0.f, 0.f);
    float4 a3 = make_float4(0.f, 0.f, 0.f, 0.f);
    int s = blk * 32 + sp;   // slot stride: BPI*32 = 2048
    #pragma unroll
    for (int it = 0; it < 8; ++it) {
        float4 v0 = xp[(size_t)(s       ) * 8 + cg];
        float4 v1 = xp[(size_t)(s + 2048) * 8 + cg];
        float4 v2 = xp[(size_t)(s + 4096) * 8 + cg];
        float4 v3 = xp[(size_t)(s + 6144) * 8 + cg];
        a0.x += v0.x; a0.y += v0.y; a0.z += v0.z; a0.w += v0.w;
        a1.x += v1.x; a1.y += v1.y; a1.z += v1.z; a1.w += v1.w;
        a2.x += v2.x; a2.y += v2.y; a2.z += v2.z; a2.w += v2.w;
        a3.x += v3.x; a3.y += v3.y; a3.z += v3.z; a3.w += v3.w;
        s += 8192;
    }
    a0.x += a1.x; a0.y += a1.y; a0.z += a1.z; a0.w += a1.w;
    a2.x += a3.x; a2.y += a3.y; a2.z += a3.z; a2.w += a3.w;
    a0.x += a2.x; a0.y += a2.y; a0.z += a2.z; a0.w += a2.w;

    __shared__ float4 red[256];
    red[tid] = a0;
    __syncthreads();
    for (int stride = 16; stride >= 1; stride >>= 1) {
        if (sp < stride) {
            float4 o = red[(sp + stride) * 8 + cg];
            a0.x += o.x; a0.y += o.y; a0.z += o.z; a0.w += o.w;
            red[tid] = a0;
        }
        __syncthreads();
    }
    if (sp == 0) {
        ((float4*)(partials + ((size_t)blk * NIMG + n) * CH))[cg] = a0;
    }
}

// ---------------------------------------------------------------------------
// Kernel 2: per-block theta recompute + column-gather with vertical corner
// reuse. One block = 8x32 px tile; thread (p,cg) owns an 8-px column.
// 4096 blocks; XCD swizzle: 512 consecutive blocks (=2 images) per XCD.
// ---------------------------------------------------------------------------
__global__ __launch_bounds__(256) void st_interp_kernel(
    const float* __restrict__ x, const float* __restrict__ partials,
    const float* __restrict__ W_loc, const float* __restrict__ b_loc,
    float* __restrict__ out) {
    const int bid = (int)blockIdx.x;
    const int swz = (bid & 7) * 512 + (bid >> 3);  // 8 XCDs contiguous
    const int n   = swz >> 8;                      // 256 blocks per image
    const int r   = swz & 255;
    const int tid = threadIdx.x;

    // ---- theta from partials (identical in every block of image n) ----
    __shared__ float red2[8][CH];
    __shared__ float th_s[8];
    {
        const int c = tid & 31, g = tid >> 5;  // g = 0..7
        float s = 0.f;
        #pragma unroll
        for (int j = 0; j < 8; ++j)
            s += partials[(size_t)((g * 8 + j) * NIMG + n) * CH + c];
        red2[g][c] = s;
        __syncthreads();
        if (g == 0) {
            float m = 0.f;
            #pragma unroll
            for (int j = 0; j < 8; ++j) m += red2[j][c];
            red2[0][c] = m * (1.0f / (float)HW);  // mean
        }
        __syncthreads();
        if (tid < 6) {
            float acc = b_loc[tid];
            for (int c2 = 0; c2 < CH; ++c2)
                acc = fmaf(red2[0][c2], W_loc[c2 * 6 + tid], acc);
            th_s[tid] = acc;
        }
        __syncthreads();
    }
    const float t00 = th_s[0], t01 = th_s[1], t02 = th_s[2];
    const float t10 = th_s[3], t11 = th_s[4], t12 = th_s[5];

    // ---- geometry: tile 8 rows x 32 cols; thread = one column of 8 px ----
    const int ty = r >> 3, tx = r & 7;             // 32 tile-rows x 8 tile-cols
    const int p  = tid >> 3;                       // column 0..31
    const int cg = tid & 7;                        // float4 channel group
    const int wo  = tx * 32 + p;
    const int ho0 = ty * 8;

    const float gx  = fmaf((float)wo, 2.0f / 255.0f, -1.0f);
    const float ayx = fmaf(t01, gx, t02);          // uy = t00*gy + ayx
    const float axx = fmaf(t11, gx, t12);          // ux = t10*gy + axx

    const float4* xp = (const float4*)(x + (size_t)n * HW * CH);
    f32x4* op = (f32x4*)(out + (size_t)n * HW * CH);

    float4 p0, p1;                 // top corner pair (rolled from prev bottom)
    int piy = -1, pix0 = -1, pix1 = -1;

    #pragma unroll
    for (int k = 0; k < 8; ++k) {
        const int ho = ho0 + k;
        const float gy = fmaf((float)ho, 2.0f / 255.0f, -1.0f);
        const float uy = (fmaf(t00, gy, ayx) + 1.0f) * 127.5f;
        const float ux = (fmaf(t10, gy, axx) + 1.0f) * 127.5f;
        const float fy = floorf(uy), fx = floorf(ux);
        const float ry = uy - fy, rx = ux - fx;
        const int iy0 = min(max((int)fy,     0), HDIM - 1);
        const int iy1 = min(max((int)fy + 1, 0), HDIM - 1);
        const int ix0 = min(max((int)fx,     0), WDIM - 1);
        const int ix1 = min(max((int)fx + 1, 0), WDIM - 1);

        // top pair: reuse previous bottom pair when indices match exactly
        if (k == 0 || !(iy0 == piy && ix0 == pix0 && ix1 == pix1)) {
            p0 = xp[(size_t)(iy0 * WDIM + ix0) * 8 + cg];
            p1 = xp[(size_t)(iy0 * WDIM + ix1) * 8 + cg];
        }
        // bottom pair: always load
        const float4 c0 = xp[(size_t)(iy1 * WDIM + ix0) * 8 + cg];
        const float4 c1 = xp[(size_t)(iy1 * WDIM + ix1) * 8 + cg];

        const float w00 = (1.0f - ry) * (1.0f - rx);
        const float w01 = (1.0f - ry) * rx;
        const float w10 = ry * (1.0f - rx);
        const float w11 = ry * rx;

        f32x4 o;
        o.x = p0.x * w00 + p1.x * w01 + c0.x * w10 + c1.x * w11;
        o.y = p0.y * w00 + p1.y * w01 + c0.y * w10 + c1.y * w11;
        o.z = p0.z * w00 + p1.z * w01 + c0.z * w10 + c1.z * w11;
        o.w = p0.w * w00 + p1.w * w01 + c0.w * w10 + c1.w * w11;
        __builtin_nontemporal_store(o, &op[(size_t)(ho * WDIM + wo) * 8 + cg]);

        // roll bottom -> next top
        p0 = c0; p1 = c1;
        piy = iy1; pix0 = ix0; pix1 = ix1;
    }
}

extern "C" void kernel_launch(void* const* d_in, const int* in_sizes, int n_in,
                              void* d_out, int out_size, void* d_ws, size_t ws_size,
                              hipStream_t stream) {
    const float* x     = (const float*)d_in[0];
    const float* W_loc = (const float*)d_in[1];
    const float* b_loc = (const float*)d_in[2];
    float* out = (float*)d_out;

    float* partials = (float*)d_ws;  // [BPI][NIMG][CH]

    st_sum_kernel<<<NIMG * BPI, 256, 0, stream>>>(x, partials);
    st_interp_kernel<<<NIMG * (HW / 256), 256, 0, stream>>>(
        x, partials, W_loc, b_loc, out);
}

// Round 12
// 63.106 us; speedup vs baseline: 1.0385x; 1.0385x over previous
//
#include <hip/hip_runtime.h>

// Problem: SpatialTransform
//   x:     (16, 256, 256, 32) f32
//   W_loc: (32, 6) f32
//   b_loc: (6) f32
//   out:   (16, 256, 256, 32) f32
//
// out = bilinear_sample(x, affine_grid(theta)), theta = mean_pool(x) @ W_loc + b_loc
//
// FINAL (R12): reproduction of the R6 config — the session's best (63.0 us).
// Plateau evidence: MLP 4/8/16 = 75.6/68.7/63.0; NT-vs-plain stores neutral;
// DMA LDS staging neutral; request-volume halving neutral; preamble size
// neutral. interp ~39us across all structures; sum ~20us (HBM read floor).

#define NIMG 16
#define HDIM 256
#define WDIM 256
#define CH   32
#define HW   (HDIM * WDIM)
#define BPI  64    // sum-kernel blocks per image

typedef float f32x4 __attribute__((ext_vector_type(4)));

// ---------------------------------------------------------------------------
// Kernel 1: per-(n,c) partial sums. 1024 blocks, 4 independent acc chains.
// partials layout: [BPI][NIMG][CH]
// ---------------------------------------------------------------------------
__global__ __launch_bounds__(256) void st_sum_kernel(
    const float* __restrict__ x, float* __restrict__ partials) {
    const int n   = blockIdx.x >> 6;
    const int blk = blockIdx.x & (BPI - 1);
    const int tid = threadIdx.x;
    const int cg  = tid & 7;    // float4 channel group
    const int sp  = tid >> 3;   // spatial slot 0..31

    const float4* xp = (const float4*)(x + (size_t)n * HW * CH);
    float4 a0 = make_float4(0.f, 0.f, 0.f, 0.f);
    float4 a1 = make_float4(0.f, 0.f, 0.f, 0.f);
    float4 a2 = make_float4(0.f, 0.f, 0.f, 0.f);
    float4 a3 = make_float4(0.f, 0.f, 0.f, 0.f);
    int s = blk * 32 + sp;   // slot stride: BPI*32 = 2048
    #pragma unroll
    for (int it = 0; it < 8; ++it) {
        float4 v0 = xp[(size_t)(s       ) * 8 + cg];
        float4 v1 = xp[(size_t)(s + 2048) * 8 + cg];
        float4 v2 = xp[(size_t)(s + 4096) * 8 + cg];
        float4 v3 = xp[(size_t)(s + 6144) * 8 + cg];
        a0.x += v0.x; a0.y += v0.y; a0.z += v0.z; a0.w += v0.w;
        a1.x += v1.x; a1.y += v1.y; a1.z += v1.z; a1.w += v1.w;
        a2.x += v2.x; a2.y += v2.y; a2.z += v2.z; a2.w += v2.w;
        a3.x += v3.x; a3.y += v3.y; a3.z += v3.z; a3.w += v3.w;
        s += 8192;
    }
    a0.x += a1.x; a0.y += a1.y; a0.z += a1.z; a0.w += a1.w;
    a2.x += a3.x; a2.y += a3.y; a2.z += a3.z; a2.w += a3.w;
    a0.x += a2.x; a0.y += a2.y; a0.z += a2.z; a0.w += a2.w;

    __shared__ float4 red[256];
    red[tid] = a0;
    __syncthreads();
    for (int stride = 16; stride >= 1; stride >>= 1) {
        if (sp < stride) {
            float4 o = red[(sp + stride) * 8 + cg];
            a0.x += o.x; a0.y += o.y; a0.z += o.z; a0.w += o.w;
            red[tid] = a0;
        }
        __syncthreads();
    }
    if (sp == 0) {
        ((float4*)(partials + ((size_t)blk * NIMG + n) * CH))[cg] = a0;
    }
}

// ---------------------------------------------------------------------------
// Kernel 2: per-block theta recompute + bilinear gather.
// One block = 4x32 pixel tile, 4 px per thread, 16 corner loads in flight.
// 8192 blocks; XCD swizzle gives each XCD 1024 consecutive blocks = 2 images.
// ---------------------------------------------------------------------------
__global__ __launch_bounds__(256) void st_interp_kernel(
    const float* __restrict__ x, const float* __restrict__ partials,
    const float* __restrict__ W_loc, const float* __restrict__ b_loc,
    float* __restrict__ out) {
    const int bid = (int)blockIdx.x;
    const int swz = (bid & 7) * 1024 + (bid >> 3);  // 8 XCDs contiguous
    const int n   = swz >> 9;                       // 512 blocks per image
    const int r   = swz & 511;
    const int tid = threadIdx.x;

    // ---- theta from partials (identical in every block of image n) ----
    __shared__ float red2[8][CH];
    __shared__ float th_s[8];
    {
        const int c = tid & 31, g = tid >> 5;  // g = 0..7
        float s = 0.f;
        #pragma unroll
        for (int j = 0; j < 8; ++j)
            s += partials[(size_t)((g * 8 + j) * NIMG + n) * CH + c];
        red2[g][c] = s;
        __syncthreads();
        if (g == 0) {
            float m = 0.f;
            #pragma unroll
            for (int j = 0; j < 8; ++j) m += red2[j][c];
            red2[0][c] = m * (1.0f / (float)HW);  // mean
        }
        __syncthreads();
        if (tid < 6) {
            float acc = b_loc[tid];
            for (int c2 = 0; c2 < CH; ++c2)
                acc = fmaf(red2[0][c2], W_loc[c2 * 6 + tid], acc);
            th_s[tid] = acc;
        }
        __syncthreads();
    }
    const float t00 = th_s[0], t01 = th_s[1], t02 = th_s[2];
    const float t10 = th_s[3], t11 = th_s[4], t12 = th_s[5];

    // ---- gather: 4x32 tile, 4 pixels per thread, 16 loads in flight ----
    const int ty = r >> 3;                         // 64 tile-rows (4 px each)
    const int tx = r & 7;                          // 8 tile-cols (32 px each)
    const int p  = tid >> 3;                       // pixel slot 0..31
    const int cg = tid & 7;                        // float4 channel group

    const int ho = ty * 4 + (p >> 3);
    const float gy = fmaf((float)ho, 2.0f / 255.0f, -1.0f);
    const float cy = fmaf(t00, gy, t02);           // uy before gx term
    const float cx = fmaf(t10, gy, t12);

    const float4* xp = (const float4*)(x + (size_t)n * HW * CH);

    int   off0[4], off1[4], off2[4], off3[4];
    float w00[4], w01[4], w10[4], w11[4];
    int   wo[4];
    #pragma unroll
    for (int k = 0; k < 4; ++k) {
        wo[k] = tx * 32 + (p & 7) + k * 8;
        const float gx = fmaf((float)wo[k], 2.0f / 255.0f, -1.0f);
        const float uy = (fmaf(t01, gx, cy) + 1.0f) * 127.5f;
        const float ux = (fmaf(t11, gx, cx) + 1.0f) * 127.5f;
        const float fy = floorf(uy), fx = floorf(ux);
        const float ry = uy - fy, rx = ux - fx;
        const int iy0 = min(max((int)fy,     0), HDIM - 1);
        const int iy1 = min(max((int)fy + 1, 0), HDIM - 1);
        const int ix0 = min(max((int)fx,     0), WDIM - 1);
        const int ix1 = min(max((int)fx + 1, 0), WDIM - 1);
        off0[k] = (iy0 * WDIM + ix0) * 8;
        off1[k] = (iy0 * WDIM + ix1) * 8;
        off2[k] = (iy1 * WDIM + ix0) * 8;
        off3[k] = (iy1 * WDIM + ix1) * 8;
        w00[k] = (1.0f - ry) * (1.0f - rx);
        w01[k] = (1.0f - ry) * rx;
        w10[k] = ry * (1.0f - rx);
        w11[k] = ry * rx;
    }

    // issue all 16 loads before any consumption
    float4 v00[4], v01[4], v10[4], v11[4];
    #pragma unroll
    for (int k = 0; k < 4; ++k) {
        v00[k] = xp[(size_t)off0[k] + cg];
        v01[k] = xp[(size_t)off1[k] + cg];
        v10[k] = xp[(size_t)off2[k] + cg];
        v11[k] = xp[(size_t)off3[k] + cg];
    }

    f32x4* op = (f32x4*)(out + (size_t)n * HW * CH);
    #pragma unroll
    for (int k = 0; k < 4; ++k) {
        f32x4 o;
        o.x = v00[k].x * w00[k] + v01[k].x * w01[k] + v10[k].x * w10[k] + v11[k].x * w11[k];
        o.y = v00[k].y * w00[k] + v01[k].y * w01[k] + v10[k].y * w10[k] + v11[k].y * w11[k];
        o.z = v00[k].z * w00[k] + v01[k].z * w01[k] + v10[k].z * w10[k] + v11[k].z * w11[k];
        o.w = v00[k].w * w00[k] + v01[k].w * w01[k] + v10[k].w * w10[k] + v11[k].w * w11[k];
        __builtin_nontemporal_store(o, &op[(size_t)(ho * WDIM + wo[k]) * 8 + cg]);
    }
}

extern "C" void kernel_launch(void* const* d_in, const int* in_sizes, int n_in,
                              void* d_out, int out_size, void* d_ws, size_t ws_size,
                              hipStream_t stream) {
    const float* x     = (const float*)d_in[0];
    const float* W_loc = (const float*)d_in[1];
    const float* b_loc = (const float*)d_in[2];
    float* out = (float*)d_out;

    float* partials = (float*)d_ws;  // [BPI][NIMG][CH]

    st_sum_kernel<<<NIMG * BPI, 256, 0, stream>>>(x, partials);
    st_interp_kernel<<<NIMG * (HW / 128), 256, 0, stream>>>(
        x, partials, W_loc, b_loc, out);
}